// Round 6
// baseline (766.553 us; speedup 1.0000x reference)
//
#include <hip/hip_runtime.h>
#include <stdint.h>

typedef __bf16 bf16_t;
typedef __bf16 bf16x8 __attribute__((ext_vector_type(8)));
typedef __bf16 bf16x4 __attribute__((ext_vector_type(4)));
typedef float f32x4 __attribute__((ext_vector_type(4)));
typedef float f32x16 __attribute__((ext_vector_type(16)));
typedef unsigned int u32;

#define DEVINL static __device__ __forceinline__

constexpr int BB = 4;
constexpr int SEQ = 2048;
constexpr int HID = 1024;
constexpr int NL = 4;
constexpr int MR = BB * SEQ;  // 8192
constexpr float LN_EPS = 1e-5f;
constexpr float MASK_NEG = -1e9f;

DEVINL f32x16 mfma32(bf16x8 a, bf16x8 b, f32x16 c) {
  return __builtin_amdgcn_mfma_f32_32x32x16_bf16(a, b, c, 0, 0, 0);
}

// async global->LDS, 16B/lane; LDS dest wave-uniform base + lane*16.
DEVINL void gload_lds16(const bf16_t* g, bf16_t* l) {
  __builtin_amdgcn_global_load_lds(
      (const __attribute__((address_space(1))) u32*)g,
      (__attribute__((address_space(3))) u32*)l, 16, 0, 0);
}

// ---------------------------------------------------------------------------
// Unified NT GEMM: BM=256 BN=128, BK=64, 512 threads (8 waves 4Mx2N),
// per-wave 64x64 via 2x2 frags of mfma_f32_32x32x16_bf16 (halves LDS-read
// bytes/FLOP and MFMA-pipe cycles vs 16x16x32 — the round-6 experiment).
// Schedule = round-5 validated 2-phase: per K-tile kt
//   p0: ds_read ALL B-frags (2n x 4ks) + A m0 frags (4ks); issue SA(kt+1)x4;
//       barrier; 8 MFMA (m0); barrier.
//   p1: ds_read A m1 frags; issue SB(kt+2)x2; barrier; 8 MFMA (m1);
//       gate vmcnt(2) (tail vmcnt(0)); barrier.
// Race/drain proofs as round 5 (identical staging counts & parity scheme).
// LDS: A 2x32KB + B 2x16KB = 96 KB. XOR slot-swizzle slot^=(row&7), applied
// as pre-swizzled gload SOURCE + swizzled ds_read col.
// EPI 0: QKV  z in {0,1,2} -> (W,bias,out); bf16 = acc + bias. grid 32*8*3.
// EPI 1: QK^T z = batch; bf16 = acc/32. grid 8*16*4.
// EPI 2: PV split-K2: z = batch*2+khalf; bf16 partial. grid 8*8*8.
// ---------------------------------------------------------------------------
template <int EPI>
__global__ __launch_bounds__(512, 2) void gemm32(
    const bf16_t* __restrict__ Ab, const bf16_t* __restrict__ B0,
    const bf16_t* __restrict__ B1, const bf16_t* __restrict__ B2,
    const float* __restrict__ bias0, const float* __restrict__ bias1,
    const float* __restrict__ bias2, bf16_t* __restrict__ o0,
    bf16_t* __restrict__ o1, bf16_t* __restrict__ o2) {
  constexpr int BM = 256, BN = 128;
  constexpr int TMn = (EPI == 0) ? (MR / 256) : (SEQ / 256);     // 32 or 8
  constexpr int TNn = (EPI == 1) ? (SEQ / 128) : (HID / 128);    // 16 or 8
  constexpr int LDA = (EPI == 2) ? SEQ : HID;
  constexpr int LDB = (EPI == 2) ? SEQ : HID;
  constexpr int LDC = (EPI == 1) ? SEQ : HID;
  constexpr int NT = 16;  // K extent 1024 (PV: per split-half)

  __shared__ bf16_t lA[2 * BM * 64];  // 64 KB
  __shared__ bf16_t lB[2 * BN * 64];  // 32 KB

  // bijective XCD swizzle (all grids % 8 == 0)
  const int nwg = gridDim.x;
  int Lb = blockIdx.x;
  Lb = (Lb & 7) * (nwg >> 3) + (Lb >> 3);
  const int z = Lb / (TMn * TNn);
  const int rem = Lb - z * (TMn * TNn);
  const int tm = rem / TNn;
  const int tn = rem - tm * TNn;
  const int brow = tm * BM, bcol = tn * BN;

  const bf16_t* A;
  const bf16_t* B;
  const float* bias = nullptr;
  bf16_t* outb = nullptr;
  if (EPI == 0) {
    A = Ab;
    B = (z == 0) ? B0 : (z == 1) ? B1 : B2;
    bias = (z == 0) ? bias0 : (z == 1) ? bias1 : bias2;
    outb = (z == 0) ? o0 : (z == 1) ? o1 : o2;
  } else if (EPI == 1) {
    A = Ab + (size_t)z * SEQ * HID;
    B = B0 + (size_t)z * SEQ * HID;
    outb = o0 + (size_t)z * SEQ * SEQ;
  } else {
    const int zb = z >> 1, kh = z & 1;
    A = Ab + (size_t)zb * SEQ * SEQ + kh * 1024;  // scores K-half
    B = B0 + (size_t)zb * HID * SEQ + kh * 1024;  // vT K-half
    outb = ((kh == 0) ? o0 : o1) + (size_t)zb * SEQ * HID;
  }

  const int t = threadIdx.x, wave = t >> 6, lane = t & 63;
  const int wm = wave >> 1, wn = wave & 1;  // 4Mx2N waves
  const int r31 = lane & 31, kb2 = lane >> 5;
  const int srow = t >> 3;               // 0..63 (64 rows per gload call)
  const int cbk = (t & 7) ^ (srow & 7);  // pre-swizzled source slot
  const bf16_t* pAs = A + (size_t)(brow + srow) * LDA + cbk * 8;
  const bf16_t* pBs = B + (size_t)(bcol + srow) * LDB + cbk * 8;
  bf16_t* lAw = lA + wave * 512;
  bf16_t* lBw = lB + wave * 512;

  // stage 64-row chunk h of K-tile X into parity X&1
#define SA(X_, h_)                                                  \
  gload_lds16(pAs + (size_t)((h_)*64) * LDA + (X_)*64,              \
              lAw + ((X_)&1) * (BM * 64) + (h_)*4096)
#define SB(X_, h_)                                                  \
  gload_lds16(pBs + (size_t)((h_)*64) * LDB + (X_)*64,              \
              lBw + ((X_)&1) * (BN * 64) + (h_)*4096)

  const char* lAc = (const char*)lA;
  const char* lBc = (const char*)lB;
  // swizzled in-row byte cols for the 4 k-slices (k = ks*16 + kb2*8 + e)
  int sX[4];
#pragma unroll
  for (int ks = 0; ks < 4; ++ks) sX[ks] = (((ks * 2 + kb2) ^ (r31 & 7)) << 4);
  const int rowA0 = wm * 64 + r31;  // + mi*32
  const int rowB0 = wn * 64 + r31;  // + ni*32

  f32x16 acc00 = {}, acc01 = {}, acc10 = {}, acc11 = {};

  // prologue: A(0) x4, B(0) x2, B(1) x2; wait all but B(1)'s 2
  SA(0, 0); SA(0, 1); SA(0, 2); SA(0, 3);
  SB(0, 0); SB(0, 1);
  SB(1, 0); SB(1, 1);
  asm volatile("s_waitcnt vmcnt(2)" ::: "memory");
  __builtin_amdgcn_s_barrier();

  for (int kt = 0; kt < NT; ++kt) {
    const char* aB = lAc + (kt & 1) * (BM * 128);
    const char* bB = lBc + (kt & 1) * (BN * 128);
    // ---- p0: all B-frags + A m0; stage A(kt+1) ----
    bf16x8 bF[2][4], a0[4];
#pragma unroll
    for (int ni = 0; ni < 2; ++ni)
#pragma unroll
      for (int ks = 0; ks < 4; ++ks)
        bF[ni][ks] = *(const bf16x8*)(bB + (rowB0 + ni * 32) * 128 + sX[ks]);
#pragma unroll
    for (int ks = 0; ks < 4; ++ks)
      a0[ks] = *(const bf16x8*)(aB + rowA0 * 128 + sX[ks]);
    if (kt + 1 < NT) { SA(kt + 1, 0); SA(kt + 1, 1); SA(kt + 1, 2); SA(kt + 1, 3); }
    __builtin_amdgcn_s_barrier();
    __builtin_amdgcn_s_setprio(1);
#pragma unroll
    for (int ks = 0; ks < 4; ++ks) {
      acc00 = mfma32(a0[ks], bF[0][ks], acc00);
      acc01 = mfma32(a0[ks], bF[1][ks], acc01);
    }
    __builtin_amdgcn_s_setprio(0);
    __builtin_amdgcn_s_barrier();
    // ---- p1: A m1; stage B(kt+2); gate ----
    bf16x8 a1[4];
#pragma unroll
    for (int ks = 0; ks < 4; ++ks)
      a1[ks] = *(const bf16x8*)(aB + (rowA0 + 32) * 128 + sX[ks]);
    if (kt + 2 < NT) { SB(kt + 2, 0); SB(kt + 2, 1); }
    __builtin_amdgcn_s_barrier();
    __builtin_amdgcn_s_setprio(1);
#pragma unroll
    for (int ks = 0; ks < 4; ++ks) {
      acc10 = mfma32(a1[ks], bF[0][ks], acc10);
      acc11 = mfma32(a1[ks], bF[1][ks], acc11);
    }
    __builtin_amdgcn_s_setprio(0);
    if (kt < NT - 2)
      asm volatile("s_waitcnt vmcnt(2)" ::: "memory");
    else
      asm volatile("s_waitcnt vmcnt(0)" ::: "memory");
    __builtin_amdgcn_s_barrier();
  }

  // C/D layout 32x32 (m74/m101): col = lane&31, row = (r&3)+8*(r>>2)+4*kb2
  const int crow = brow + wm * 64 + 4 * kb2;
  const int ccol = bcol + wn * 64 + r31;
#pragma unroll
  for (int mi = 0; mi < 2; ++mi) {
#pragma unroll
    for (int ni = 0; ni < 2; ++ni) {
      const f32x16 av = (mi == 0) ? (ni == 0 ? acc00 : acc01)
                                  : (ni == 0 ? acc10 : acc11);
      const int col = ccol + ni * 32;
      const float badd = (EPI == 0) ? bias[col] : 0.f;
#pragma unroll
      for (int r = 0; r < 16; ++r) {
        const int row = crow + mi * 32 + (r & 3) + 8 * (r >> 2);
        const float vv = av[r];
        if (EPI == 0)
          outb[(size_t)row * LDC + col] = (bf16_t)(vv + badd);
        else if (EPI == 1)
          outb[(size_t)row * LDC + col] = (bf16_t)(vv * 0.03125f);
        else
          outb[(size_t)row * LDC + col] = (bf16_t)vv;
      }
    }
  }
#undef SA
#undef SB
}

// ---------------------------------------------------------------------------
__global__ __launch_bounds__(256) void cast_f32_bf16(
    const float* __restrict__ in, bf16_t* __restrict__ out, long n4) {
  const long stride = (long)gridDim.x * blockDim.x;
  for (long i = (long)blockIdx.x * blockDim.x + threadIdx.x; i < n4;
       i += stride) {
    f32x4 x = *(const f32x4*)(in + i * 4);
    bf16x4 o;
#pragma unroll
    for (int j = 0; j < 4; ++j) o[j] = (bf16_t)x[j];
    *(bf16x4*)(out + i * 4) = o;
  }
}

// v [z][SEQ][HID] -> vT [z][HID][SEQ]
__global__ __launch_bounds__(256) void transpose_bf16_k(
    const bf16_t* __restrict__ in, bf16_t* __restrict__ out) {
  __shared__ bf16_t tile[64][72];
  const int z = blockIdx.z;
  const bf16_t* src = in + (size_t)z * SEQ * HID;
  bf16_t* dst = out + (size_t)z * SEQ * HID;
  const int r0 = blockIdx.x * 64;
  const int c0 = blockIdx.y * 64;
  const int t = threadIdx.x;
  const int tx = t & 7;
  const int ty = t >> 3;
#pragma unroll
  for (int i = 0; i < 2; ++i) {
    const int r = ty + i * 32;
    bf16x8 vv = *(const bf16x8*)(src + (size_t)(r0 + r) * HID + c0 + tx * 8);
    *(bf16x8*)&tile[r][tx * 8] = vv;
  }
  __syncthreads();
#pragma unroll
  for (int i = 0; i < 2; ++i) {
    const int c = ty + i * 32;
    bf16x8 ov;
#pragma unroll
    for (int j = 0; j < 8; ++j) ov[j] = tile[tx * 8 + j][c];
    *(bf16x8*)(dst + (size_t)(c0 + c) * SEQ + r0 + tx * 8) = ov;
  }
}

// in-place masked softmax over rows of [B*S, S] bf16
__global__ __launch_bounds__(256) void softmax_rows(
    bf16_t* __restrict__ sc, const int* __restrict__ mask) {
  const int row = blockIdx.x;
  const int b = row >> 11;
  bf16_t* p = sc + (size_t)row * SEQ;
  const int* mrow = mask + (size_t)b * SEQ;
  const int t = threadIdx.x;
  const int wave = t >> 6;
  const int lane = t & 63;

  bf16x8 v = *(const bf16x8*)(p + t * 8);
  const int4 m0 = *(const int4*)(mrow + t * 8);
  const int4 m1 = *(const int4*)(mrow + t * 8 + 4);
  const int mk[8] = {m0.x, m0.y, m0.z, m0.w, m1.x, m1.y, m1.z, m1.w};

  float vals[8];
  float mx = -3.4e38f;
#pragma unroll
  for (int j = 0; j < 8; ++j) {
    float s = (float)v[j];
    if (mk[j] == 0) s = MASK_NEG;
    vals[j] = s;
    mx = fmaxf(mx, s);
  }
#pragma unroll
  for (int off = 32; off > 0; off >>= 1)
    mx = fmaxf(mx, __shfl_xor(mx, off, 64));
  __shared__ float red[4];
  if (lane == 0) red[wave] = mx;
  __syncthreads();
  mx = fmaxf(fmaxf(red[0], red[1]), fmaxf(red[2], red[3]));
  __syncthreads();

  float sum = 0.f;
#pragma unroll
  for (int j = 0; j < 8; ++j) {
    vals[j] = __expf(vals[j] - mx);
    sum += vals[j];
  }
#pragma unroll
  for (int off = 32; off > 0; off >>= 1) sum += __shfl_xor(sum, off, 64);
  if (lane == 0) red[wave] = sum;
  __syncthreads();
  sum = red[0] + red[1] + red[2] + red[3];
  const float inv = 1.f / sum;
  bf16x8 o;
#pragma unroll
  for (int j = 0; j < 8; ++j) o[j] = (bf16_t)(vals[j] * inv);
  *(bf16x8*)(p + t * 8) = o;
}

// y = x + attn0 + attn1 (bf16 split-K partials); LayerNorm(y) -> xout (+bf16)
__global__ __launch_bounds__(256) void resid_ln(
    const bf16_t* __restrict__ part0, const bf16_t* __restrict__ part1,
    const float* __restrict__ xin, const float* __restrict__ lnw,
    const float* __restrict__ lnb, float* __restrict__ xout,
    bf16_t* __restrict__ xbout) {
  const int row = blockIdx.x;
  const int t = threadIdx.x;
  const int wave = t >> 6;
  const int lane = t & 63;
  const size_t base = (size_t)row * HID + t * 4;
  const bf16x4 a0 = *(const bf16x4*)(part0 + base);
  const bf16x4 a1 = *(const bf16x4*)(part1 + base);
  const f32x4 xv = *(const f32x4*)(xin + base);
  f32x4 y;
#pragma unroll
  for (int j = 0; j < 4; ++j) y[j] = (float)a0[j] + (float)a1[j] + xv[j];
  float s1 = y[0] + y[1] + y[2] + y[3];
  float s2 = y[0] * y[0] + y[1] * y[1] + y[2] * y[2] + y[3] * y[3];
#pragma unroll
  for (int off = 32; off > 0; off >>= 1) {
    s1 += __shfl_xor(s1, off, 64);
    s2 += __shfl_xor(s2, off, 64);
  }
  __shared__ float red[8];
  if (lane == 0) {
    red[wave] = s1;
    red[4 + wave] = s2;
  }
  __syncthreads();
  s1 = red[0] + red[1] + red[2] + red[3];
  s2 = red[4] + red[5] + red[6] + red[7];
  const float mu = s1 * (1.f / HID);
  const float var = s2 * (1.f / HID) - mu * mu;
  const float rs = rsqrtf(var + LN_EPS);
  const f32x4 wv = *(const f32x4*)(lnw + t * 4);
  const f32x4 bv = *(const f32x4*)(lnb + t * 4);
  f32x4 o;
#pragma unroll
  for (int j = 0; j < 4; ++j) o[j] = wv[j] * ((y[j] - mu) * rs) + bv[j];
  *(f32x4*)(xout + base) = o;
  if (xbout != nullptr) {
    bf16x4 ob;
#pragma unroll
    for (int j = 0; j < 4; ++j) ob[j] = (bf16_t)o[j];
    *(bf16x4*)(xbout + base) = ob;
  }
}

// ---------------------------------------------------------------------------
extern "C" void kernel_launch(void* const* d_in, const int* in_sizes, int n_in,
                              void* d_out, int out_size, void* d_ws,
                              size_t ws_size, hipStream_t stream) {
  const float* x_in = (const float*)d_in[0];
  const int* mask = (const int*)d_in[1];
  const float* Wq = (const float*)d_in[2];
  const float* bq = (const float*)d_in[3];
  const float* Wk = (const float*)d_in[4];
  const float* bk = (const float*)d_in[5];
  const float* Wv = (const float*)d_in[6];
  const float* bv = (const float*)d_in[7];
  const float* lnw = (const float*)d_in[8];
  const float* lnb = (const float*)d_in[9];
  float* out = (float*)d_out;

  char* ws = (char*)d_ws;
  size_t off = 0;
  auto alloc = [&](size_t bytes) {
    char* p = ws + off;
    off += (bytes + 255) & ~(size_t)255;
    return (void*)p;
  };
  const size_t LHH = (size_t)NL * HID * HID;
  bf16_t* wqb = (bf16_t*)alloc(LHH * 2);
  bf16_t* wkb = (bf16_t*)alloc(LHH * 2);
  bf16_t* wvb = (bf16_t*)alloc(LHH * 2);
  bf16_t* xb = (bf16_t*)alloc((size_t)MR * HID * 2);
  bf16_t* q = (bf16_t*)alloc((size_t)MR * HID * 2);
  bf16_t* k = (bf16_t*)alloc((size_t)MR * HID * 2);
  bf16_t* v = (bf16_t*)alloc((size_t)MR * HID * 2);
  bf16_t* vT = (bf16_t*)alloc((size_t)MR * HID * 2);
  bf16_t* scores = (bf16_t*)alloc((size_t)BB * SEQ * SEQ * 2);
  bf16_t* attn0 = (bf16_t*)alloc((size_t)MR * HID * 2);
  bf16_t* attn1 = (bf16_t*)alloc((size_t)MR * HID * 2);
  float* xbuf = (float*)alloc((size_t)MR * HID * 4);
  if (off > ws_size) return;

  cast_f32_bf16<<<2048, 256, 0, stream>>>(Wq, wqb, (long)(LHH / 4));
  cast_f32_bf16<<<2048, 256, 0, stream>>>(Wk, wkb, (long)(LHH / 4));
  cast_f32_bf16<<<2048, 256, 0, stream>>>(Wv, wvb, (long)(LHH / 4));
  cast_f32_bf16<<<2048, 256, 0, stream>>>(x_in, xb, (long)((size_t)MR * HID / 4));

  for (int l = 0; l < NL; ++l) {
    const size_t wo = (size_t)l * HID * HID;
    // QKV projections: grid 3 * 32 * 8 = 768 (3 exact CU rounds)
    gemm32<0><<<768, 512, 0, stream>>>(xb, wqb + wo, wkb + wo, wvb + wo,
                                       bq + (size_t)l * HID, bk + (size_t)l * HID,
                                       bv + (size_t)l * HID, q, k, v);
    // V^T for the PV GEMM
    transpose_bf16_k<<<dim3(SEQ / 64, HID / 64, BB), 256, 0, stream>>>(v, vT);
    // scores = q k^T / sqrt(H): grid 4 * 8 * 16 = 512 (2 exact rounds)
    gemm32<1><<<512, 512, 0, stream>>>(q, k, nullptr, nullptr, nullptr, nullptr,
                                       nullptr, scores, nullptr, nullptr);
    // masked softmax (in place)
    softmax_rows<<<MR, 256, 0, stream>>>(scores, mask);
    // attn partials = probs @ v (split-K 2): grid 8 * 8 * 8 = 512
    gemm32<2><<<512, 512, 0, stream>>>(scores, vT, nullptr, nullptr, nullptr,
                                       nullptr, nullptr, attn0, attn1, nullptr);
    // residual + LayerNorm (+ bf16 recast for next layer)
    const float* xi = (l == 0) ? x_in : xbuf;
    float* xo = (l == NL - 1) ? out : xbuf;
    bf16_t* xbo = (l == NL - 1) ? nullptr : xb;
    resid_ln<<<MR, 256, 0, stream>>>(attn0, attn1, xi, lnw + (size_t)l * HID,
                                     lnb + (size_t)l * HID, xo, xbo);
  }
}

// Round 7
// 706.959 us; speedup vs baseline: 1.0843x; 1.0843x over previous
//
#include <hip/hip_runtime.h>
#include <stdint.h>

typedef __bf16 bf16_t;
typedef __bf16 bf16x8 __attribute__((ext_vector_type(8)));
typedef __bf16 bf16x4 __attribute__((ext_vector_type(4)));
typedef float f32x4 __attribute__((ext_vector_type(4)));
typedef float f32x16 __attribute__((ext_vector_type(16)));
typedef unsigned int u32;

#define DEVINL static __device__ __forceinline__

constexpr int BB = 4;
constexpr int SEQ = 2048;
constexpr int HID = 1024;
constexpr int NL = 4;
constexpr int MR = BB * SEQ;  // 8192
constexpr float LN_EPS = 1e-5f;

DEVINL f32x4 mfma16(bf16x8 a, bf16x8 b, f32x4 c) {
  return __builtin_amdgcn_mfma_f32_16x16x32_bf16(a, b, c, 0, 0, 0);
}
DEVINL f32x16 mfma32(bf16x8 a, bf16x8 b, f32x16 c) {
  return __builtin_amdgcn_mfma_f32_32x32x16_bf16(a, b, c, 0, 0, 0);
}

// async global->LDS, 16B/lane; LDS dest wave-uniform base + lane*16.
DEVINL void gload_lds16(const bf16_t* g, bf16_t* l) {
  __builtin_amdgcn_global_load_lds(
      (const __attribute__((address_space(1))) u32*)g,
      (__attribute__((address_space(3))) u32*)l, 16, 0, 0);
}

// ---------------------------------------------------------------------------
// QKV GEMM (round-6 validated structure): BM=256 BN=128 BK=64, 8 waves 4Mx2N,
// per-wave 64x64 = 2x2 of mfma_f32_32x32x16_bf16. 2-phase/K-tile, counted
// vmcnt(2) gate, XOR slot-swizzle (0 measured... see notes), gload_lds.
// NEW this round: grid order z-INNERMOST (logical = tm*24 + tn*3 + z) so each
// XCD's contiguous chunk shares x-rows across all 3 weight matrices and all
// tn -> x fetched ~once from HBM instead of 3x.
// ---------------------------------------------------------------------------
__global__ __launch_bounds__(512, 2) void gemm_qkv(
    const bf16_t* __restrict__ xb, const bf16_t* __restrict__ w0,
    const bf16_t* __restrict__ w1, const bf16_t* __restrict__ w2,
    const float* __restrict__ bias0, const float* __restrict__ bias1,
    const float* __restrict__ bias2, bf16_t* __restrict__ o0,
    bf16_t* __restrict__ o1, bf16_t* __restrict__ o2) {
  constexpr int BM = 256, BN = 128, NT = 16;

  __shared__ bf16_t lA[2 * BM * 64];  // 64 KB
  __shared__ bf16_t lB[2 * BN * 64];  // 32 KB

  // bijective XCD swizzle; grid = 768 (% 8 == 0)
  const int nwg = gridDim.x;
  int Lb = blockIdx.x;
  Lb = (Lb & 7) * (nwg >> 3) + (Lb >> 3);
  const int z = Lb % 3;
  const int r2 = Lb / 3;
  const int tn = r2 & 7;
  const int tm = r2 >> 3;
  const int brow = tm * BM, bcol = tn * BN;

  const bf16_t* B = (z == 0) ? w0 : (z == 1) ? w1 : w2;
  const float* bias = (z == 0) ? bias0 : (z == 1) ? bias1 : bias2;
  bf16_t* outb = (z == 0) ? o0 : (z == 1) ? o1 : o2;

  const int t = threadIdx.x, wave = t >> 6, lane = t & 63;
  const int wm = wave >> 1, wn = wave & 1;  // 4Mx2N
  const int r31 = lane & 31, kb2 = lane >> 5;
  const int srow = t >> 3;
  const int cbk = (t & 7) ^ (srow & 7);  // pre-swizzled source slot
  const bf16_t* pAs = xb + (size_t)(brow + srow) * HID + cbk * 8;
  const bf16_t* pBs = B + (size_t)(bcol + srow) * HID + cbk * 8;
  bf16_t* lAw = lA + wave * 512;
  bf16_t* lBw = lB + wave * 512;

#define SA(X_, h_)                                                  \
  gload_lds16(pAs + (size_t)((h_)*64) * HID + (X_)*64,              \
              lAw + ((X_)&1) * (BM * 64) + (h_)*4096)
#define SB(X_, h_)                                                  \
  gload_lds16(pBs + (size_t)((h_)*64) * HID + (X_)*64,              \
              lBw + ((X_)&1) * (BN * 64) + (h_)*4096)

  const char* lAc = (const char*)lA;
  const char* lBc = (const char*)lB;
  int sX[4];
#pragma unroll
  for (int ks = 0; ks < 4; ++ks) sX[ks] = (((ks * 2 + kb2) ^ (r31 & 7)) << 4);
  const int rowA0 = wm * 64 + r31;
  const int rowB0 = wn * 64 + r31;

  f32x16 acc00 = {}, acc01 = {}, acc10 = {}, acc11 = {};

  SA(0, 0); SA(0, 1); SA(0, 2); SA(0, 3);
  SB(0, 0); SB(0, 1);
  SB(1, 0); SB(1, 1);
  asm volatile("s_waitcnt vmcnt(2)" ::: "memory");
  __builtin_amdgcn_s_barrier();

  for (int kt = 0; kt < NT; ++kt) {
    const char* aB = lAc + (kt & 1) * (BM * 128);
    const char* bB = lBc + (kt & 1) * (BN * 128);
    bf16x8 bF[2][4], a0[4];
#pragma unroll
    for (int ni = 0; ni < 2; ++ni)
#pragma unroll
      for (int ks = 0; ks < 4; ++ks)
        bF[ni][ks] = *(const bf16x8*)(bB + (rowB0 + ni * 32) * 128 + sX[ks]);
#pragma unroll
    for (int ks = 0; ks < 4; ++ks)
      a0[ks] = *(const bf16x8*)(aB + rowA0 * 128 + sX[ks]);
    if (kt + 1 < NT) { SA(kt + 1, 0); SA(kt + 1, 1); SA(kt + 1, 2); SA(kt + 1, 3); }
    __builtin_amdgcn_s_barrier();
    __builtin_amdgcn_s_setprio(1);
#pragma unroll
    for (int ks = 0; ks < 4; ++ks) {
      acc00 = mfma32(a0[ks], bF[0][ks], acc00);
      acc01 = mfma32(a0[ks], bF[1][ks], acc01);
    }
    __builtin_amdgcn_s_setprio(0);
    __builtin_amdgcn_s_barrier();
    bf16x8 a1[4];
#pragma unroll
    for (int ks = 0; ks < 4; ++ks)
      a1[ks] = *(const bf16x8*)(aB + (rowA0 + 32) * 128 + sX[ks]);
    if (kt + 2 < NT) { SB(kt + 2, 0); SB(kt + 2, 1); }
    __builtin_amdgcn_s_barrier();
    __builtin_amdgcn_s_setprio(1);
#pragma unroll
    for (int ks = 0; ks < 4; ++ks) {
      acc10 = mfma32(a1[ks], bF[0][ks], acc10);
      acc11 = mfma32(a1[ks], bF[1][ks], acc11);
    }
    __builtin_amdgcn_s_setprio(0);
    if (kt < NT - 2)
      asm volatile("s_waitcnt vmcnt(2)" ::: "memory");
    else
      asm volatile("s_waitcnt vmcnt(0)" ::: "memory");
    __builtin_amdgcn_s_barrier();
  }

  // C/D 32x32 layout (m74/m101): col = lane&31, row = (r&3)+8*(r>>2)+4*kb2
  const int crow = brow + wm * 64 + 4 * kb2;
  const int ccol = bcol + wn * 64 + r31;
#pragma unroll
  for (int mi = 0; mi < 2; ++mi) {
#pragma unroll
    for (int ni = 0; ni < 2; ++ni) {
      const f32x16 av = (mi == 0) ? (ni == 0 ? acc00 : acc01)
                                  : (ni == 0 ? acc10 : acc11);
      const int col = ccol + ni * 32;
      const float badd = bias[col];
#pragma unroll
      for (int r = 0; r < 16; ++r) {
        const int row = crow + mi * 32 + (r & 3) + 8 * (r >> 2);
        outb[(size_t)row * HID + col] = (bf16_t)(av[r] + badd);
      }
    }
  }
#undef SA
#undef SB
}

// ---------------------------------------------------------------------------
// QK / PV GEMM: round-4 256^2 4-phase 16x16 structure (best measured for
// these shapes; conflicts 0). Epilogues changed this round:
// EPI 1 (QK): P = mask ? exp(s/32) : 0, written bf16 (softmax w/o max-sub:
//   |s| <~ 7 so exp safe; normalization applied in PV epilogue).
// EPI 2 (PV split-K2): out = acc * rinv[row] (rinv = 1/rowsum of P).
// ---------------------------------------------------------------------------
template <int EPI>
__global__ __launch_bounds__(512, 2) void gemm8(
    const bf16_t* __restrict__ Ab, const bf16_t* __restrict__ B0,
    const int* __restrict__ maskp, const float* __restrict__ rsum,
    bf16_t* __restrict__ o0, bf16_t* __restrict__ o1) {
  constexpr int TM = 8;
  constexpr int TN = (EPI == 1) ? 8 : 4;
  constexpr int LDA = (EPI == 2) ? SEQ : HID;
  constexpr int LDB = (EPI == 2) ? SEQ : HID;
  constexpr int LDC = (EPI == 1) ? SEQ : HID;
  constexpr int NT = 16;

  __shared__ bf16_t lA[2 * 16384];
  __shared__ bf16_t lB[2 * 16384];

  const int nwg = gridDim.x;
  int Lb = blockIdx.x;
  Lb = (Lb & 7) * (nwg >> 3) + (Lb >> 3);
  const int z = Lb / (TM * TN);
  const int rem = Lb - z * (TM * TN);
  const int tm = rem / TN;
  const int tn = rem - tm * TN;
  const int brow = tm * 256, bcol = tn * 256;

  const bf16_t* A;
  const bf16_t* B;
  bf16_t* outb;
  int zb = 0;
  if (EPI == 1) {
    A = Ab + (size_t)z * SEQ * HID;
    B = B0 + (size_t)z * SEQ * HID;
    outb = o0 + (size_t)z * SEQ * SEQ;
  } else {
    zb = z >> 1;
    const int kh = z & 1;
    A = Ab + (size_t)zb * SEQ * SEQ + kh * 1024;  // scores K-half
    B = B0 + (size_t)zb * HID * SEQ + kh * 1024;  // vT K-half
    outb = ((kh == 0) ? o0 : o1) + (size_t)zb * SEQ * HID;
  }

  const int t = threadIdx.x, wave = t >> 6, lane = t & 63;
  const int wm = wave >> 2, wn = wave & 3;
  const int fr = lane & 15, kb = lane >> 4;
  const int srow = t >> 3;
  const int cbk = (t & 7) ^ (srow & 7);
  const bf16_t* pAs = A + (size_t)(brow + srow) * LDA + cbk * 8;
  const bf16_t* pBs = B + (size_t)(bcol + srow) * LDB + cbk * 8;
  bf16_t* lAw = lA + wave * 512;
  bf16_t* lBw = lB + wave * 512;

#define SA(X_, h_)                                                  \
  gload_lds16(pAs + (size_t)((h_)*64) * LDA + (X_)*64,              \
              lAw + ((X_)&1) * 16384 + (h_)*4096)
#define SB(X_, h_)                                                  \
  gload_lds16(pBs + (size_t)((h_)*64) * LDB + (X_)*64,              \
              lBw + ((X_)&1) * 16384 + (h_)*4096)

  const char* lAc = (const char*)lA;
  const char* lBc = (const char*)lB;
  const int cX0 = ((kb ^ (fr & 7)) << 4);
  const int cX1 = cX0 ^ 64;
  const int bRowOff = (wn & 1) * 64;

  f32x4 acc[8][4] = {};

  SA(0, 0); SA(0, 1); SA(0, 2); SA(0, 3);
  SB(0, 0); SB(0, 1); SB(0, 2); SB(0, 3);
  SA(1, 0); SA(1, 2);
  SB(1, 0); SB(1, 1); SB(1, 2); SB(1, 3);
  asm volatile("s_waitcnt vmcnt(6)" ::: "memory");
  __builtin_amdgcn_s_barrier();

  for (int kt = 0; kt < NT; ++kt) {
    const char* aB = lAc + (kt & 1) * 32768 + wm * 16384;
    const char* bB = lBc + (kt & 1) * 32768 + (wn >> 1) * 16384;
    bf16x8 bf_[4][2];
#pragma unroll
    for (int p = 0; p < 4; ++p) {
      if (p == 0) {
#pragma unroll
        for (int n = 0; n < 4; ++n) {
          const int rb = (bRowOff + n * 16 + fr) * 128;
          bf_[n][0] = *(const bf16x8*)(bB + rb + cX0);
          bf_[n][1] = *(const bf16x8*)(bB + rb + cX1);
        }
      }
      const int ra0 = (p * 32 + fr) * 128;
      const int ra1 = (p * 32 + 16 + fr) * 128;
      bf16x8 a00 = *(const bf16x8*)(aB + ra0 + cX0);
      bf16x8 a01 = *(const bf16x8*)(aB + ra0 + cX1);
      bf16x8 a10 = *(const bf16x8*)(aB + ra1 + cX0);
      bf16x8 a11 = *(const bf16x8*)(aB + ra1 + cX1);
      if (p == 0 && kt + 1 < NT) { SA(kt + 1, 1); SA(kt + 1, 3); }
      if (p == 1 && kt + 2 < NT) { SB(kt + 2, 0); SB(kt + 2, 1); }
      if (p == 2 && kt + 2 < NT) { SA(kt + 2, 0); SA(kt + 2, 2); }
      if (p == 3 && kt + 2 < NT) { SB(kt + 2, 2); SB(kt + 2, 3); }
      __builtin_amdgcn_s_barrier();
      __builtin_amdgcn_s_setprio(1);
#pragma unroll
      for (int n = 0; n < 4; ++n) {
        acc[2 * p][n] = mfma16(a00, bf_[n][0], acc[2 * p][n]);
        acc[2 * p][n] = mfma16(a01, bf_[n][1], acc[2 * p][n]);
        acc[2 * p + 1][n] = mfma16(a10, bf_[n][0], acc[2 * p + 1][n]);
        acc[2 * p + 1][n] = mfma16(a11, bf_[n][1], acc[2 * p + 1][n]);
      }
      __builtin_amdgcn_s_setprio(0);
      if (p == 3) {
        if (kt < NT - 3)
          asm volatile("s_waitcnt vmcnt(6)" ::: "memory");
        else
          asm volatile("s_waitcnt vmcnt(0)" ::: "memory");
      }
      __builtin_amdgcn_s_barrier();
    }
  }

  // C/D layout (m89): col = lane&15, row = (lane>>4)*4 + j
  const int qr = lane >> 4;
  const int crow = brow + wm * 128 + qr * 4;
  const int ccol = bcol + wn * 64 + fr;
  if (EPI == 1) {
    const int* mrow = maskp + (size_t)z * SEQ;
#pragma unroll
    for (int n = 0; n < 4; ++n) {
      const int col = ccol + n * 16;
      const int mv = mrow[col];
#pragma unroll
      for (int m = 0; m < 8; ++m) {
        const int row = crow + m * 16;
#pragma unroll
        for (int j = 0; j < 4; ++j) {
          const float vv = acc[m][n][j];
          outb[(size_t)(row + j) * LDC + col] =
              mv ? (bf16_t)__expf(vv * 0.03125f) : (bf16_t)0.f;
        }
      }
    }
  } else {
    const float* rv = rsum + (size_t)zb * SEQ;
#pragma unroll
    for (int m = 0; m < 8; ++m) {
      const int row = crow + m * 16;
#pragma unroll
      for (int j = 0; j < 4; ++j) {
        const float ri = rv[row + j];
#pragma unroll
        for (int n = 0; n < 4; ++n) {
          const int col = ccol + n * 16;
          outb[(size_t)(row + j) * LDC + col] = (bf16_t)(acc[m][n][j] * ri);
        }
      }
    }
  }
#undef SA
#undef SB
}

// ---------------------------------------------------------------------------
// merged casts: y=0..2 -> Wq/Wk/Wv, y=3 -> x
__global__ __launch_bounds__(256) void cast4(
    const float* __restrict__ s0, const float* __restrict__ s1,
    const float* __restrict__ s2, const float* __restrict__ s3,
    bf16_t* __restrict__ d0, bf16_t* __restrict__ d1,
    bf16_t* __restrict__ d2, bf16_t* __restrict__ d3, long nW4, long nX4) {
  const int y = blockIdx.y;
  const float* in = (y == 0) ? s0 : (y == 1) ? s1 : (y == 2) ? s2 : s3;
  bf16_t* out = (y == 0) ? d0 : (y == 1) ? d1 : (y == 2) ? d2 : d3;
  const long n4 = (y == 3) ? nX4 : nW4;
  const long stride = (long)gridDim.x * blockDim.x;
  for (long i = (long)blockIdx.x * blockDim.x + threadIdx.x; i < n4;
       i += stride) {
    f32x4 x = *(const f32x4*)(in + i * 4);
    bf16x4 o;
#pragma unroll
    for (int j = 0; j < 4; ++j) o[j] = (bf16_t)x[j];
    *(bf16x4*)(out + i * 4) = o;
  }
}

// v [z][SEQ][HID] -> vT [z][HID][SEQ]
__global__ __launch_bounds__(256) void transpose_bf16_k(
    const bf16_t* __restrict__ in, bf16_t* __restrict__ out) {
  __shared__ bf16_t tile[64][72];
  const int z = blockIdx.z;
  const bf16_t* src = in + (size_t)z * SEQ * HID;
  bf16_t* dst = out + (size_t)z * SEQ * HID;
  const int r0 = blockIdx.x * 64;
  const int c0 = blockIdx.y * 64;
  const int t = threadIdx.x;
  const int tx = t & 7;
  const int ty = t >> 3;
#pragma unroll
  for (int i = 0; i < 2; ++i) {
    const int r = ty + i * 32;
    bf16x8 vv = *(const bf16x8*)(src + (size_t)(r0 + r) * HID + c0 + tx * 8);
    *(bf16x8*)&tile[r][tx * 8] = vv;
  }
  __syncthreads();
#pragma unroll
  for (int i = 0; i < 2; ++i) {
    const int c = ty + i * 32;
    bf16x8 ov;
#pragma unroll
    for (int j = 0; j < 8; ++j) ov[j] = tile[tx * 8 + j][c];
    *(bf16x8*)(dst + (size_t)(c0 + c) * SEQ + r0 + tx * 8) = ov;
  }
}

// rinv[row] = 1 / sum(P[row, :]) over bf16 P rows of length SEQ
__global__ __launch_bounds__(256) void rowsum_inv(
    const bf16_t* __restrict__ P, float* __restrict__ rinv) {
  const int row = blockIdx.x;
  const bf16_t* p = P + (size_t)row * SEQ;
  const int t = threadIdx.x;
  const int wave = t >> 6;
  const int lane = t & 63;
  bf16x8 v = *(const bf16x8*)(p + t * 8);
  float s = 0.f;
#pragma unroll
  for (int j = 0; j < 8; ++j) s += (float)v[j];
#pragma unroll
  for (int off = 32; off > 0; off >>= 1) s += __shfl_xor(s, off, 64);
  __shared__ float red[4];
  if (lane == 0) red[wave] = s;
  __syncthreads();
  if (t == 0) {
    const float tot = red[0] + red[1] + red[2] + red[3];
    rinv[row] = 1.f / tot;
  }
}

// y = x + attn0 + attn1 (bf16 partials, already rinv-scaled); LayerNorm(y)
__global__ __launch_bounds__(256) void resid_ln(
    const bf16_t* __restrict__ part0, const bf16_t* __restrict__ part1,
    const float* __restrict__ xin, const float* __restrict__ lnw,
    const float* __restrict__ lnb, float* __restrict__ xout,
    bf16_t* __restrict__ xbout) {
  const int row = blockIdx.x;
  const int t = threadIdx.x;
  const int wave = t >> 6;
  const int lane = t & 63;
  const size_t base = (size_t)row * HID + t * 4;
  const bf16x4 a0 = *(const bf16x4*)(part0 + base);
  const bf16x4 a1 = *(const bf16x4*)(part1 + base);
  const f32x4 xv = *(const f32x4*)(xin + base);
  f32x4 y;
#pragma unroll
  for (int j = 0; j < 4; ++j) y[j] = (float)a0[j] + (float)a1[j] + xv[j];
  float s1 = y[0] + y[1] + y[2] + y[3];
  float s2 = y[0] * y[0] + y[1] * y[1] + y[2] * y[2] + y[3] * y[3];
#pragma unroll
  for (int off = 32; off > 0; off >>= 1) {
    s1 += __shfl_xor(s1, off, 64);
    s2 += __shfl_xor(s2, off, 64);
  }
  __shared__ float red[8];
  if (lane == 0) {
    red[wave] = s1;
    red[4 + wave] = s2;
  }
  __syncthreads();
  s1 = red[0] + red[1] + red[2] + red[3];
  s2 = red[4] + red[5] + red[6] + red[7];
  const float mu = s1 * (1.f / HID);
  const float var = s2 * (1.f / HID) - mu * mu;
  const float rs = rsqrtf(var + LN_EPS);
  const f32x4 wv = *(const f32x4*)(lnw + t * 4);
  const f32x4 bv = *(const f32x4*)(lnb + t * 4);
  f32x4 o;
#pragma unroll
  for (int j = 0; j < 4; ++j) o[j] = wv[j] * ((y[j] - mu) * rs) + bv[j];
  *(f32x4*)(xout + base) = o;
  if (xbout != nullptr) {
    bf16x4 ob;
#pragma unroll
    for (int j = 0; j < 4; ++j) ob[j] = (bf16_t)o[j];
    *(bf16x4*)(xbout + base) = ob;
  }
}

// ---------------------------------------------------------------------------
extern "C" void kernel_launch(void* const* d_in, const int* in_sizes, int n_in,
                              void* d_out, int out_size, void* d_ws,
                              size_t ws_size, hipStream_t stream) {
  const float* x_in = (const float*)d_in[0];
  const int* mask = (const int*)d_in[1];
  const float* Wq = (const float*)d_in[2];
  const float* bq = (const float*)d_in[3];
  const float* Wk = (const float*)d_in[4];
  const float* bk = (const float*)d_in[5];
  const float* Wv = (const float*)d_in[6];
  const float* bv = (const float*)d_in[7];
  const float* lnw = (const float*)d_in[8];
  const float* lnb = (const float*)d_in[9];
  float* out = (float*)d_out;

  char* ws = (char*)d_ws;
  size_t off = 0;
  auto alloc = [&](size_t bytes) {
    char* p = ws + off;
    off += (bytes + 255) & ~(size_t)255;
    return (void*)p;
  };
  const size_t LHH = (size_t)NL * HID * HID;
  bf16_t* wqb = (bf16_t*)alloc(LHH * 2);
  bf16_t* wkb = (bf16_t*)alloc(LHH * 2);
  bf16_t* wvb = (bf16_t*)alloc(LHH * 2);
  bf16_t* xb = (bf16_t*)alloc((size_t)MR * HID * 2);
  bf16_t* q = (bf16_t*)alloc((size_t)MR * HID * 2);
  bf16_t* k = (bf16_t*)alloc((size_t)MR * HID * 2);
  bf16_t* v = (bf16_t*)alloc((size_t)MR * HID * 2);
  bf16_t* vT = (bf16_t*)alloc((size_t)MR * HID * 2);
  bf16_t* scores = (bf16_t*)alloc((size_t)BB * SEQ * SEQ * 2);
  bf16_t* attn0 = (bf16_t*)alloc((size_t)MR * HID * 2);
  bf16_t* attn1 = (bf16_t*)alloc((size_t)MR * HID * 2);
  float* rinv = (float*)alloc((size_t)MR * 4);
  float* xbuf = (float*)alloc((size_t)MR * HID * 4);
  if (off > ws_size) return;

  cast4<<<dim3(1024, 4), 256, 0, stream>>>(Wq, Wk, Wv, x_in, wqb, wkb, wvb, xb,
                                           (long)(LHH / 4),
                                           (long)((size_t)MR * HID / 4));

  for (int l = 0; l < NL; ++l) {
    const size_t wo = (size_t)l * HID * HID;
    // QKV: grid 32*8*3 = 768 (3 exact CU rounds), z-inner for x L2 reuse
    gemm_qkv<<<768, 512, 0, stream>>>(xb, wqb + wo, wkb + wo, wvb + wo,
                                      bq + (size_t)l * HID,
                                      bk + (size_t)l * HID,
                                      bv + (size_t)l * HID, q, k, v);
    // V^T for the PV GEMM
    transpose_bf16_k<<<dim3(SEQ / 64, HID / 64, BB), 256, 0, stream>>>(v, vT);
    // P = mask * exp(q k^T / 32)  (unnormalized softmax): grid 4*8*8 = 256
    gemm8<1><<<256, 512, 0, stream>>>(q, k, mask, nullptr, scores, nullptr);
    // rinv = 1/rowsum(P)
    rowsum_inv<<<MR, 256, 0, stream>>>(scores, rinv);
    // attn partials = (P @ v) * rinv (split-K 2): grid 8*8*4*2 = 256
    gemm8<2><<<256, 512, 0, stream>>>(scores, vT, nullptr, rinv, attn0, attn1);
    // residual + LayerNorm (+ bf16 recast for next layer)
    const float* xi = (l == 0) ? x_in : xbuf;
    float* xo = (l == NL - 1) ? out : xbuf;
    bf16_t* xbo = (l == NL - 1) ? nullptr : xb;
    resid_ln<<<MR, 256, 0, stream>>>(attn0, attn1, xi, lnw + (size_t)l * HID,
                                     lnb + (size_t)l * HID, xo, xbo);
  }
}

// Round 8
// 678.899 us; speedup vs baseline: 1.1291x; 1.0413x over previous
//
#include <hip/hip_runtime.h>
#include <stdint.h>

typedef __bf16 bf16_t;
typedef __bf16 bf16x8 __attribute__((ext_vector_type(8)));
typedef __bf16 bf16x4 __attribute__((ext_vector_type(4)));
typedef float f32x4 __attribute__((ext_vector_type(4)));
typedef float f32x16 __attribute__((ext_vector_type(16)));
typedef unsigned int u32;

#define DEVINL static __device__ __forceinline__

constexpr int BB = 4;
constexpr int SEQ = 2048;
constexpr int HID = 1024;
constexpr int NL = 4;
constexpr int MR = BB * SEQ;  // 8192
constexpr float LN_EPS = 1e-5f;

DEVINL f32x4 mfma16(bf16x8 a, bf16x8 b, f32x4 c) {
  return __builtin_amdgcn_mfma_f32_16x16x32_bf16(a, b, c, 0, 0, 0);
}
DEVINL f32x16 mfma32(bf16x8 a, bf16x8 b, f32x16 c) {
  return __builtin_amdgcn_mfma_f32_32x32x16_bf16(a, b, c, 0, 0, 0);
}

// async global->LDS, 16B/lane; LDS dest wave-uniform base + lane*16.
DEVINL void gload_lds16(const bf16_t* g, bf16_t* l) {
  __builtin_amdgcn_global_load_lds(
      (const __attribute__((address_space(1))) u32*)g,
      (__attribute__((address_space(3))) u32*)l, 16, 0, 0);
}

// ---------------------------------------------------------------------------
// QKV GEMM: BM=256 BN=128 BK=64, 8 waves 4Mx2N, per-wave 64x64 = 2x2 of
// mfma_f32_32x32x16_bf16. 2-phase/K-tile, counted vmcnt(2), XOR slot-swizzle,
// gload_lds. Decode z-OUTER (round-6 order; round-7's z-inner decode after
// the XCD swizzle scrambled locality: FETCH 49->86 MB).
// z==2 (V) writes TRANSPOSED: vT[batch][h][s] — replaces the transpose
// kernel. kb2-pair lanes fully cover each 64B line -> no write amplification.
// ---------------------------------------------------------------------------
__global__ __launch_bounds__(512, 2) void gemm_qkv(
    const bf16_t* __restrict__ xb, const bf16_t* __restrict__ w0,
    const bf16_t* __restrict__ w1, const bf16_t* __restrict__ w2,
    const float* __restrict__ bias0, const float* __restrict__ bias1,
    const float* __restrict__ bias2, bf16_t* __restrict__ o0,
    bf16_t* __restrict__ o1, bf16_t* __restrict__ vT) {
  constexpr int BM = 256, BN = 128, NT = 16;

  __shared__ bf16_t lA[2 * BM * 64];  // 64 KB
  __shared__ bf16_t lB[2 * BN * 64];  // 32 KB

  // bijective XCD swizzle; grid = 768 (% 8 == 0); z outermost
  const int nwg = gridDim.x;
  int Lb = blockIdx.x;
  Lb = (Lb & 7) * (nwg >> 3) + (Lb >> 3);
  const int z = Lb >> 8;           // / 256
  const int rem = Lb & 255;
  const int tm = rem >> 3;         // / 8
  const int tn = rem & 7;
  const int brow = tm * BM, bcol = tn * BN;

  const bf16_t* B = (z == 0) ? w0 : (z == 1) ? w1 : w2;
  const float* bias = (z == 0) ? bias0 : (z == 1) ? bias1 : bias2;

  const int t = threadIdx.x, wave = t >> 6, lane = t & 63;
  const int wm = wave >> 1, wn = wave & 1;  // 4Mx2N
  const int r31 = lane & 31, kb2 = lane >> 5;
  const int srow = t >> 3;
  const int cbk = (t & 7) ^ (srow & 7);  // pre-swizzled source slot
  const bf16_t* pAs = xb + (size_t)(brow + srow) * HID + cbk * 8;
  const bf16_t* pBs = B + (size_t)(bcol + srow) * HID + cbk * 8;
  bf16_t* lAw = lA + wave * 512;
  bf16_t* lBw = lB + wave * 512;

#define SA(X_, h_)                                                  \
  gload_lds16(pAs + (size_t)((h_)*64) * HID + (X_)*64,              \
              lAw + ((X_)&1) * (BM * 64) + (h_)*4096)
#define SB(X_, h_)                                                  \
  gload_lds16(pBs + (size_t)((h_)*64) * HID + (X_)*64,              \
              lBw + ((X_)&1) * (BN * 64) + (h_)*4096)

  const char* lAc = (const char*)lA;
  const char* lBc = (const char*)lB;
  int sX[4];
#pragma unroll
  for (int ks = 0; ks < 4; ++ks) sX[ks] = (((ks * 2 + kb2) ^ (r31 & 7)) << 4);
  const int rowA0 = wm * 64 + r31;
  const int rowB0 = wn * 64 + r31;

  f32x16 acc00 = {}, acc01 = {}, acc10 = {}, acc11 = {};

  SA(0, 0); SA(0, 1); SA(0, 2); SA(0, 3);
  SB(0, 0); SB(0, 1);
  SB(1, 0); SB(1, 1);
  asm volatile("s_waitcnt vmcnt(2)" ::: "memory");
  __builtin_amdgcn_s_barrier();

  for (int kt = 0; kt < NT; ++kt) {
    const char* aB = lAc + (kt & 1) * (BM * 128);
    const char* bB = lBc + (kt & 1) * (BN * 128);
    bf16x8 bF[2][4], a0[4];
#pragma unroll
    for (int ni = 0; ni < 2; ++ni)
#pragma unroll
      for (int ks = 0; ks < 4; ++ks)
        bF[ni][ks] = *(const bf16x8*)(bB + (rowB0 + ni * 32) * 128 + sX[ks]);
#pragma unroll
    for (int ks = 0; ks < 4; ++ks)
      a0[ks] = *(const bf16x8*)(aB + rowA0 * 128 + sX[ks]);
    if (kt + 1 < NT) { SA(kt + 1, 0); SA(kt + 1, 1); SA(kt + 1, 2); SA(kt + 1, 3); }
    __builtin_amdgcn_s_barrier();
    __builtin_amdgcn_s_setprio(1);
#pragma unroll
    for (int ks = 0; ks < 4; ++ks) {
      acc00 = mfma32(a0[ks], bF[0][ks], acc00);
      acc01 = mfma32(a0[ks], bF[1][ks], acc01);
    }
    __builtin_amdgcn_s_setprio(0);
    __builtin_amdgcn_s_barrier();
    bf16x8 a1[4];
#pragma unroll
    for (int ks = 0; ks < 4; ++ks)
      a1[ks] = *(const bf16x8*)(aB + (rowA0 + 32) * 128 + sX[ks]);
    if (kt + 2 < NT) { SB(kt + 2, 0); SB(kt + 2, 1); }
    __builtin_amdgcn_s_barrier();
    __builtin_amdgcn_s_setprio(1);
#pragma unroll
    for (int ks = 0; ks < 4; ++ks) {
      acc10 = mfma32(a1[ks], bF[0][ks], acc10);
      acc11 = mfma32(a1[ks], bF[1][ks], acc11);
    }
    __builtin_amdgcn_s_setprio(0);
    if (kt < NT - 2)
      asm volatile("s_waitcnt vmcnt(2)" ::: "memory");
    else
      asm volatile("s_waitcnt vmcnt(0)" ::: "memory");
    __builtin_amdgcn_s_barrier();
  }

  // C/D 32x32 layout (m74/m101): col = lane&31, row = (r&3)+8*(r>>2)+4*kb2
  const int crow = brow + wm * 64 + 4 * kb2;
  const int ccol = bcol + wn * 64 + r31;
  if (z < 2) {
    bf16_t* outb = (z == 0) ? o0 : o1;
#pragma unroll
    for (int mi = 0; mi < 2; ++mi) {
#pragma unroll
      for (int ni = 0; ni < 2; ++ni) {
        const f32x16 av = (mi == 0) ? (ni == 0 ? acc00 : acc01)
                                    : (ni == 0 ? acc10 : acc11);
        const int col = ccol + ni * 32;
        const float badd = bias[col];
#pragma unroll
        for (int r = 0; r < 16; ++r) {
          const int row = crow + mi * 32 + (r & 3) + 8 * (r >> 2);
          outb[(size_t)row * HID + col] = (bf16_t)(av[r] + badd);
        }
      }
    }
  } else {
    // V: write transposed vT[batch][h=col][s=row&2047] as bf16x4 runs
    const int batch = brow >> 11;
    bf16_t* vt = vT + (size_t)batch * HID * SEQ;
    const int s00 = (crow & 2047);
#pragma unroll
    for (int mi = 0; mi < 2; ++mi) {
#pragma unroll
      for (int ni = 0; ni < 2; ++ni) {
        const f32x16 av = (mi == 0) ? (ni == 0 ? acc00 : acc01)
                                    : (ni == 0 ? acc10 : acc11);
        const int col = ccol + ni * 32;
        const float badd = bias[col];
#pragma unroll
        for (int g = 0; g < 4; ++g) {
          const int s0 = s00 + mi * 32 + 8 * g;
          bf16x4 ov;
#pragma unroll
          for (int i = 0; i < 4; ++i) ov[i] = (bf16_t)(av[4 * g + i] + badd);
          *(bf16x4*)(vt + (size_t)col * SEQ + s0) = ov;
        }
      }
    }
  }
#undef SA
#undef SB
}

// ---------------------------------------------------------------------------
// QK / PV GEMM: 256^2 4-phase 16x16 structure.
// EPI 1 (QK): P = mask ? exp(s/32) : 0 (bf16, unnormalized); fused rowsum:
//   16-lane shfl reduce per row + one atomicAdd per row per wave into rsum.
// EPI 2 (PV split-K2): out = acc / rsum[row] (bf16 partial).
// ---------------------------------------------------------------------------
template <int EPI>
__global__ __launch_bounds__(512, 2) void gemm8(
    const bf16_t* __restrict__ Ab, const bf16_t* __restrict__ B0,
    const int* __restrict__ maskp, float* __restrict__ rsum,
    bf16_t* __restrict__ o0, bf16_t* __restrict__ o1) {
  constexpr int TM = 8;
  constexpr int TN = (EPI == 1) ? 8 : 4;
  constexpr int LDA = (EPI == 2) ? SEQ : HID;
  constexpr int LDB = (EPI == 2) ? SEQ : HID;
  constexpr int LDC = (EPI == 1) ? SEQ : HID;
  constexpr int NT = 16;

  __shared__ bf16_t lA[2 * 16384];
  __shared__ bf16_t lB[2 * 16384];

  const int nwg = gridDim.x;
  int Lb = blockIdx.x;
  Lb = (Lb & 7) * (nwg >> 3) + (Lb >> 3);
  const int z = Lb / (TM * TN);
  const int rem = Lb - z * (TM * TN);
  const int tm = rem / TN;
  const int tn = rem - tm * TN;
  const int brow = tm * 256, bcol = tn * 256;

  const bf16_t* A;
  const bf16_t* B;
  bf16_t* outb;
  int zb = 0;
  if (EPI == 1) {
    A = Ab + (size_t)z * SEQ * HID;
    B = B0 + (size_t)z * SEQ * HID;
    outb = o0 + (size_t)z * SEQ * SEQ;
  } else {
    zb = z >> 1;
    const int kh = z & 1;
    A = Ab + (size_t)zb * SEQ * SEQ + kh * 1024;  // scores K-half
    B = B0 + (size_t)zb * HID * SEQ + kh * 1024;  // vT K-half
    outb = ((kh == 0) ? o0 : o1) + (size_t)zb * SEQ * HID;
  }

  const int t = threadIdx.x, wave = t >> 6, lane = t & 63;
  const int wm = wave >> 2, wn = wave & 3;
  const int fr = lane & 15, kb = lane >> 4;
  const int srow = t >> 3;
  const int cbk = (t & 7) ^ (srow & 7);
  const bf16_t* pAs = A + (size_t)(brow + srow) * LDA + cbk * 8;
  const bf16_t* pBs = B + (size_t)(bcol + srow) * LDB + cbk * 8;
  bf16_t* lAw = lA + wave * 512;
  bf16_t* lBw = lB + wave * 512;

#define SA(X_, h_)                                                  \
  gload_lds16(pAs + (size_t)((h_)*64) * LDA + (X_)*64,              \
              lAw + ((X_)&1) * 16384 + (h_)*4096)
#define SB(X_, h_)                                                  \
  gload_lds16(pBs + (size_t)((h_)*64) * LDB + (X_)*64,              \
              lBw + ((X_)&1) * 16384 + (h_)*4096)

  const char* lAc = (const char*)lA;
  const char* lBc = (const char*)lB;
  const int cX0 = ((kb ^ (fr & 7)) << 4);
  const int cX1 = cX0 ^ 64;
  const int bRowOff = (wn & 1) * 64;

  f32x4 acc[8][4] = {};

  SA(0, 0); SA(0, 1); SA(0, 2); SA(0, 3);
  SB(0, 0); SB(0, 1); SB(0, 2); SB(0, 3);
  SA(1, 0); SA(1, 2);
  SB(1, 0); SB(1, 1); SB(1, 2); SB(1, 3);
  asm volatile("s_waitcnt vmcnt(6)" ::: "memory");
  __builtin_amdgcn_s_barrier();

  for (int kt = 0; kt < NT; ++kt) {
    const char* aB = lAc + (kt & 1) * 32768 + wm * 16384;
    const char* bB = lBc + (kt & 1) * 32768 + (wn >> 1) * 16384;
    bf16x8 bf_[4][2];
#pragma unroll
    for (int p = 0; p < 4; ++p) {
      if (p == 0) {
#pragma unroll
        for (int n = 0; n < 4; ++n) {
          const int rb = (bRowOff + n * 16 + fr) * 128;
          bf_[n][0] = *(const bf16x8*)(bB + rb + cX0);
          bf_[n][1] = *(const bf16x8*)(bB + rb + cX1);
        }
      }
      const int ra0 = (p * 32 + fr) * 128;
      const int ra1 = (p * 32 + 16 + fr) * 128;
      bf16x8 a00 = *(const bf16x8*)(aB + ra0 + cX0);
      bf16x8 a01 = *(const bf16x8*)(aB + ra0 + cX1);
      bf16x8 a10 = *(const bf16x8*)(aB + ra1 + cX0);
      bf16x8 a11 = *(const bf16x8*)(aB + ra1 + cX1);
      if (p == 0 && kt + 1 < NT) { SA(kt + 1, 1); SA(kt + 1, 3); }
      if (p == 1 && kt + 2 < NT) { SB(kt + 2, 0); SB(kt + 2, 1); }
      if (p == 2 && kt + 2 < NT) { SA(kt + 2, 0); SA(kt + 2, 2); }
      if (p == 3 && kt + 2 < NT) { SB(kt + 2, 2); SB(kt + 2, 3); }
      __builtin_amdgcn_s_barrier();
      __builtin_amdgcn_s_setprio(1);
#pragma unroll
      for (int n = 0; n < 4; ++n) {
        acc[2 * p][n] = mfma16(a00, bf_[n][0], acc[2 * p][n]);
        acc[2 * p][n] = mfma16(a01, bf_[n][1], acc[2 * p][n]);
        acc[2 * p + 1][n] = mfma16(a10, bf_[n][0], acc[2 * p + 1][n]);
        acc[2 * p + 1][n] = mfma16(a11, bf_[n][1], acc[2 * p + 1][n]);
      }
      __builtin_amdgcn_s_setprio(0);
      if (p == 3) {
        if (kt < NT - 3)
          asm volatile("s_waitcnt vmcnt(6)" ::: "memory");
        else
          asm volatile("s_waitcnt vmcnt(0)" ::: "memory");
      }
      __builtin_amdgcn_s_barrier();
    }
  }

  // C/D layout (m89): col = lane&15, row = (lane>>4)*4 + j
  const int qr = lane >> 4;
  const int crow = brow + wm * 128 + qr * 4;
  const int ccol = bcol + wn * 64 + fr;
  if (EPI == 1) {
    const int* mrow = maskp + (size_t)z * SEQ;
    float* rs = rsum + (size_t)z * SEQ;
    int mv[4];
#pragma unroll
    for (int n = 0; n < 4; ++n) mv[n] = mrow[ccol + n * 16];
#pragma unroll
    for (int m = 0; m < 8; ++m) {
      const int row = crow + m * 16;
#pragma unroll
      for (int j = 0; j < 4; ++j) {
        float rp = 0.f;
#pragma unroll
        for (int n = 0; n < 4; ++n) {
          const int col = ccol + n * 16;
          const float p = mv[n] ? __expf(acc[m][n][j] * 0.03125f) : 0.f;
          outb[(size_t)(row + j) * LDC + col] = (bf16_t)p;
          rp += p;
        }
        rp += __shfl_xor(rp, 1, 64);
        rp += __shfl_xor(rp, 2, 64);
        rp += __shfl_xor(rp, 4, 64);
        rp += __shfl_xor(rp, 8, 64);
        if (fr == 0) atomicAdd(&rs[row + j], rp);
      }
    }
  } else {
    const float* rv = rsum + (size_t)zb * SEQ;
#pragma unroll
    for (int m = 0; m < 8; ++m) {
      const int row = crow + m * 16;
#pragma unroll
      for (int j = 0; j < 4; ++j) {
        const float ri = 1.f / rv[row + j];
#pragma unroll
        for (int n = 0; n < 4; ++n) {
          const int col = ccol + n * 16;
          outb[(size_t)(row + j) * LDC + col] = (bf16_t)(acc[m][n][j] * ri);
        }
      }
    }
  }
#undef SA
#undef SB
}

// ---------------------------------------------------------------------------
// merged casts: y=0..2 -> Wq/Wk/Wv, y=3 -> x
__global__ __launch_bounds__(256) void cast4(
    const float* __restrict__ s0, const float* __restrict__ s1,
    const float* __restrict__ s2, const float* __restrict__ s3,
    bf16_t* __restrict__ d0, bf16_t* __restrict__ d1,
    bf16_t* __restrict__ d2, bf16_t* __restrict__ d3, long nW4, long nX4) {
  const int y = blockIdx.y;
  const float* in = (y == 0) ? s0 : (y == 1) ? s1 : (y == 2) ? s2 : s3;
  bf16_t* out = (y == 0) ? d0 : (y == 1) ? d1 : (y == 2) ? d2 : d3;
  const long n4 = (y == 3) ? nX4 : nW4;
  const long stride = (long)gridDim.x * blockDim.x;
  for (long i = (long)blockIdx.x * blockDim.x + threadIdx.x; i < n4;
       i += stride) {
    f32x4 x = *(const f32x4*)(in + i * 4);
    bf16x4 o;
#pragma unroll
    for (int j = 0; j < 4; ++j) o[j] = (bf16_t)x[j];
    *(bf16x4*)(out + i * 4) = o;
  }
}

// y = resid + attn0 + attn1; LayerNorm(y).
// resid source: xinf (f32, layer 0) else xinb (bf16). Outputs: optional f32
// xout (final layer) and/or bf16 xbout (next layer input; may alias xinb).
__global__ __launch_bounds__(256) void resid_ln(
    const bf16_t* __restrict__ part0, const bf16_t* __restrict__ part1,
    const float* __restrict__ xinf, const bf16_t* __restrict__ xinb,
    const float* __restrict__ lnw, const float* __restrict__ lnb,
    float* __restrict__ xout, bf16_t* __restrict__ xbout) {
  const int row = blockIdx.x;
  const int t = threadIdx.x;
  const int wave = t >> 6;
  const int lane = t & 63;
  const size_t base = (size_t)row * HID + t * 4;
  const bf16x4 a0 = *(const bf16x4*)(part0 + base);
  const bf16x4 a1 = *(const bf16x4*)(part1 + base);
  f32x4 xv;
  if (xinf != nullptr) {
    xv = *(const f32x4*)(xinf + base);
  } else {
    const bf16x4 xbv = *(const bf16x4*)(xinb + base);
#pragma unroll
    for (int j = 0; j < 4; ++j) xv[j] = (float)xbv[j];
  }
  f32x4 y;
#pragma unroll
  for (int j = 0; j < 4; ++j) y[j] = (float)a0[j] + (float)a1[j] + xv[j];
  float s1 = y[0] + y[1] + y[2] + y[3];
  float s2 = y[0] * y[0] + y[1] * y[1] + y[2] * y[2] + y[3] * y[3];
#pragma unroll
  for (int off = 32; off > 0; off >>= 1) {
    s1 += __shfl_xor(s1, off, 64);
    s2 += __shfl_xor(s2, off, 64);
  }
  __shared__ float red[8];
  if (lane == 0) {
    red[wave] = s1;
    red[4 + wave] = s2;
  }
  __syncthreads();
  s1 = red[0] + red[1] + red[2] + red[3];
  s2 = red[4] + red[5] + red[6] + red[7];
  const float mu = s1 * (1.f / HID);
  const float var = s2 * (1.f / HID) - mu * mu;
  const float rs = rsqrtf(var + LN_EPS);
  const f32x4 wv = *(const f32x4*)(lnw + t * 4);
  const f32x4 bv = *(const f32x4*)(lnb + t * 4);
  f32x4 o;
#pragma unroll
  for (int j = 0; j < 4; ++j) o[j] = wv[j] * ((y[j] - mu) * rs) + bv[j];
  if (xout != nullptr) *(f32x4*)(xout + base) = o;
  if (xbout != nullptr) {
    bf16x4 ob;
#pragma unroll
    for (int j = 0; j < 4; ++j) ob[j] = (bf16_t)o[j];
    *(bf16x4*)(xbout + base) = ob;
  }
}

// ---------------------------------------------------------------------------
extern "C" void kernel_launch(void* const* d_in, const int* in_sizes, int n_in,
                              void* d_out, int out_size, void* d_ws,
                              size_t ws_size, hipStream_t stream) {
  const float* x_in = (const float*)d_in[0];
  const int* mask = (const int*)d_in[1];
  const float* Wq = (const float*)d_in[2];
  const float* bq = (const float*)d_in[3];
  const float* Wk = (const float*)d_in[4];
  const float* bk = (const float*)d_in[5];
  const float* Wv = (const float*)d_in[6];
  const float* bv = (const float*)d_in[7];
  const float* lnw = (const float*)d_in[8];
  const float* lnb = (const float*)d_in[9];
  float* out = (float*)d_out;

  char* ws = (char*)d_ws;
  size_t off = 0;
  auto alloc = [&](size_t bytes) {
    char* p = ws + off;
    off += (bytes + 255) & ~(size_t)255;
    return (void*)p;
  };
  const size_t LHH = (size_t)NL * HID * HID;
  bf16_t* wqb = (bf16_t*)alloc(LHH * 2);
  bf16_t* wkb = (bf16_t*)alloc(LHH * 2);
  bf16_t* wvb = (bf16_t*)alloc(LHH * 2);
  bf16_t* xb = (bf16_t*)alloc((size_t)MR * HID * 2);
  bf16_t* q = (bf16_t*)alloc((size_t)MR * HID * 2);
  bf16_t* k = (bf16_t*)alloc((size_t)MR * HID * 2);
  bf16_t* vT = (bf16_t*)alloc((size_t)MR * HID * 2);
  bf16_t* scores = (bf16_t*)alloc((size_t)BB * SEQ * SEQ * 2);
  bf16_t* attn0 = (bf16_t*)alloc((size_t)MR * HID * 2);
  bf16_t* attn1 = (bf16_t*)alloc((size_t)MR * HID * 2);
  float* rsum = (float*)alloc((size_t)MR * 4);
  if (off > ws_size) return;

  cast4<<<dim3(1024, 4), 256, 0, stream>>>(Wq, Wk, Wv, x_in, wqb, wkb, wvb, xb,
                                           (long)(LHH / 4),
                                           (long)((size_t)MR * HID / 4));

  for (int l = 0; l < NL; ++l) {
    const size_t wo = (size_t)l * HID * HID;
    // QKV: grid 32*8*3 = 768, z-outer decode; V written transposed
    gemm_qkv<<<768, 512, 0, stream>>>(xb, wqb + wo, wkb + wo, wvb + wo,
                                      bq + (size_t)l * HID,
                                      bk + (size_t)l * HID,
                                      bv + (size_t)l * HID, q, k, vT);
    // rsum = 0, then P = mask*exp(qk^T/32) with fused atomic rowsum
    hipMemsetAsync(rsum, 0, (size_t)MR * 4, stream);
    gemm8<1><<<256, 512, 0, stream>>>(q, k, mask, rsum, scores, nullptr);
    // attn partials = (P @ v) / rsum (split-K 2)
    gemm8<2><<<256, 512, 0, stream>>>(scores, vT, nullptr, rsum, attn0, attn1);
    // residual + LayerNorm
    const float* xif = (l == 0) ? x_in : nullptr;
    float* xo = (l == NL - 1) ? out : nullptr;
    bf16_t* xbo = (l == NL - 1) ? nullptr : xb;
    resid_ln<<<MR, 256, 0, stream>>>(attn0, attn1, xif, xb,
                                     lnw + (size_t)l * HID,
                                     lnb + (size_t)l * HID, xo, xbo);
  }
}

// Round 9
// 656.718 us; speedup vs baseline: 1.1672x; 1.0338x over previous
//
#include <hip/hip_runtime.h>
#include <stdint.h>

typedef __bf16 bf16_t;
typedef __bf16 bf16x8 __attribute__((ext_vector_type(8)));
typedef __bf16 bf16x4 __attribute__((ext_vector_type(4)));
typedef float f32x4 __attribute__((ext_vector_type(4)));
typedef float f32x16 __attribute__((ext_vector_type(16)));
typedef unsigned int u32;

#define DEVINL static __device__ __forceinline__

constexpr int BB = 4;
constexpr int SEQ = 2048;
constexpr int HID = 1024;
constexpr int NL = 4;
constexpr int MR = BB * SEQ;  // 8192
constexpr float LN_EPS = 1e-5f;

DEVINL f32x4 mfma16(bf16x8 a, bf16x8 b, f32x4 c) {
  return __builtin_amdgcn_mfma_f32_16x16x32_bf16(a, b, c, 0, 0, 0);
}
DEVINL f32x16 mfma32(bf16x8 a, bf16x8 b, f32x16 c) {
  return __builtin_amdgcn_mfma_f32_32x32x16_bf16(a, b, c, 0, 0, 0);
}

// async global->LDS, 16B/lane; LDS dest wave-uniform base + lane*16.
DEVINL void gload_lds16(const bf16_t* g, bf16_t* l) {
  __builtin_amdgcn_global_load_lds(
      (const __attribute__((address_space(1))) u32*)g,
      (__attribute__((address_space(3))) u32*)l, 16, 0, 0);
}

// ---------------------------------------------------------------------------
// QKV GEMM: BM=256 BN=128 BK=64, 8 waves 4Mx2N, per-wave 64x64 = 2x2 of
// mfma_f32_32x32x16_bf16. 2-phase/K-tile, counted vmcnt(2), XOR slot-swizzle,
// gload_lds, z-outer decode.
// z==2 (V): vT written via per-wave LDS transpose (this round's change) —
// acc's 4-consecutive-row registers become bf16x4 LDS stores in transposed
// orientation; global stores are 128B-contiguous segments (8 lanes x 16B).
// Safe LDS reuse: after the K-loop's final barrier all MFMA ds_reads have
// completed (each precedes its consuming MFMA, which precedes the barrier);
// each wave uses a disjoint 9KB region afterward.
// ---------------------------------------------------------------------------
__global__ __launch_bounds__(512, 2) void gemm_qkv(
    const bf16_t* __restrict__ xb, const bf16_t* __restrict__ w0,
    const bf16_t* __restrict__ w1, const bf16_t* __restrict__ w2,
    const float* __restrict__ bias0, const float* __restrict__ bias1,
    const float* __restrict__ bias2, bf16_t* __restrict__ o0,
    bf16_t* __restrict__ o1, bf16_t* __restrict__ vT) {
  constexpr int BM = 256, BN = 128, NT = 16;

  __shared__ bf16_t smem[2 * BM * 64 + 2 * BN * 64];  // 96 KB pool
  bf16_t* lA = smem;                 // 64 KB (A dbuf)
  bf16_t* lB = smem + 2 * BM * 64;   // 32 KB (B dbuf)

  // bijective XCD swizzle; grid = 768 (% 8 == 0); z outermost
  const int nwg = gridDim.x;
  int Lb = blockIdx.x;
  Lb = (Lb & 7) * (nwg >> 3) + (Lb >> 3);
  const int z = Lb >> 8;           // / 256
  const int rem = Lb & 255;
  const int tm = rem >> 3;         // / 8
  const int tn = rem & 7;
  const int brow = tm * BM, bcol = tn * BN;

  const bf16_t* B = (z == 0) ? w0 : (z == 1) ? w1 : w2;
  const float* bias = (z == 0) ? bias0 : (z == 1) ? bias1 : bias2;

  const int t = threadIdx.x, wave = t >> 6, lane = t & 63;
  const int wm = wave >> 1, wn = wave & 1;  // 4Mx2N
  const int r31 = lane & 31, kb2 = lane >> 5;
  const int srow = t >> 3;
  const int cbk = (t & 7) ^ (srow & 7);  // pre-swizzled source slot
  const bf16_t* pAs = xb + (size_t)(brow + srow) * HID + cbk * 8;
  const bf16_t* pBs = B + (size_t)(bcol + srow) * HID + cbk * 8;
  bf16_t* lAw = lA + wave * 512;
  bf16_t* lBw = lB + wave * 512;

#define SA(X_, h_)                                                  \
  gload_lds16(pAs + (size_t)((h_)*64) * HID + (X_)*64,              \
              lAw + ((X_)&1) * (BM * 64) + (h_)*4096)
#define SB(X_, h_)                                                  \
  gload_lds16(pBs + (size_t)((h_)*64) * HID + (X_)*64,              \
              lBw + ((X_)&1) * (BN * 64) + (h_)*4096)

  const char* lAc = (const char*)lA;
  const char* lBc = (const char*)lB;
  int sX[4];
#pragma unroll
  for (int ks = 0; ks < 4; ++ks) sX[ks] = (((ks * 2 + kb2) ^ (r31 & 7)) << 4);
  const int rowA0 = wm * 64 + r31;
  const int rowB0 = wn * 64 + r31;

  f32x16 acc00 = {}, acc01 = {}, acc10 = {}, acc11 = {};

  SA(0, 0); SA(0, 1); SA(0, 2); SA(0, 3);
  SB(0, 0); SB(0, 1);
  SB(1, 0); SB(1, 1);
  asm volatile("s_waitcnt vmcnt(2)" ::: "memory");
  __builtin_amdgcn_s_barrier();

  for (int kt = 0; kt < NT; ++kt) {
    const char* aB = lAc + (kt & 1) * (BM * 128);
    const char* bB = lBc + (kt & 1) * (BN * 128);
    bf16x8 bF[2][4], a0[4];
#pragma unroll
    for (int ni = 0; ni < 2; ++ni)
#pragma unroll
      for (int ks = 0; ks < 4; ++ks)
        bF[ni][ks] = *(const bf16x8*)(bB + (rowB0 + ni * 32) * 128 + sX[ks]);
#pragma unroll
    for (int ks = 0; ks < 4; ++ks)
      a0[ks] = *(const bf16x8*)(aB + rowA0 * 128 + sX[ks]);
    if (kt + 1 < NT) { SA(kt + 1, 0); SA(kt + 1, 1); SA(kt + 1, 2); SA(kt + 1, 3); }
    __builtin_amdgcn_s_barrier();
    __builtin_amdgcn_s_setprio(1);
#pragma unroll
    for (int ks = 0; ks < 4; ++ks) {
      acc00 = mfma32(a0[ks], bF[0][ks], acc00);
      acc01 = mfma32(a0[ks], bF[1][ks], acc01);
    }
    __builtin_amdgcn_s_setprio(0);
    __builtin_amdgcn_s_barrier();
    bf16x8 a1[4];
#pragma unroll
    for (int ks = 0; ks < 4; ++ks)
      a1[ks] = *(const bf16x8*)(aB + (rowA0 + 32) * 128 + sX[ks]);
    if (kt + 2 < NT) { SB(kt + 2, 0); SB(kt + 2, 1); }
    __builtin_amdgcn_s_barrier();
    __builtin_amdgcn_s_setprio(1);
#pragma unroll
    for (int ks = 0; ks < 4; ++ks) {
      acc10 = mfma32(a1[ks], bF[0][ks], acc10);
      acc11 = mfma32(a1[ks], bF[1][ks], acc11);
    }
    __builtin_amdgcn_s_setprio(0);
    if (kt < NT - 2)
      asm volatile("s_waitcnt vmcnt(2)" ::: "memory");
    else
      asm volatile("s_waitcnt vmcnt(0)" ::: "memory");
    __builtin_amdgcn_s_barrier();
  }

  // C/D 32x32 layout (m74/m101): col = lane&31, row = (r&3)+8*(r>>2)+4*kb2
  if (z < 2) {
    const int crow = brow + wm * 64 + 4 * kb2;
    const int ccol = bcol + wn * 64 + r31;
    bf16_t* outb = (z == 0) ? o0 : o1;
#pragma unroll
    for (int mi = 0; mi < 2; ++mi) {
#pragma unroll
      for (int ni = 0; ni < 2; ++ni) {
        const f32x16 av = (mi == 0) ? (ni == 0 ? acc00 : acc01)
                                    : (ni == 0 ? acc10 : acc11);
        const int col = ccol + ni * 32;
        const float badd = bias[col];
#pragma unroll
        for (int r = 0; r < 16; ++r) {
          const int row = crow + mi * 32 + (r & 3) + 8 * (r >> 2);
          outb[(size_t)row * HID + col] = (bf16_t)(av[r] + badd);
        }
      }
    }
  } else {
    // V -> vT[batch][h][s] via per-wave LDS transpose.
    bf16_t* tp = smem + wave * (64 * 72);  // 64 x 64 tile, stride 72 (16B-mult)
#pragma unroll
    for (int mi = 0; mi < 2; ++mi) {
#pragma unroll
      for (int ni = 0; ni < 2; ++ni) {
        const f32x16 av = (mi == 0) ? (ni == 0 ? acc00 : acc01)
                                    : (ni == 0 ? acc10 : acc11);
        const int cl = r31 + ni * 32;  // tile-local output col
        const float badd = bias[bcol + wn * 64 + cl];
#pragma unroll
        for (int g = 0; g < 4; ++g) {
          const int rl = mi * 32 + 8 * g + 4 * kb2;  // tile-local row base
          bf16x4 ov;
#pragma unroll
          for (int i = 0; i < 4; ++i) ov[i] = (bf16_t)(av[4 * g + i] + badd);
          *(bf16x4*)(tp + cl * 72 + rl) = ov;  // transposed orientation
        }
      }
    }
    asm volatile("s_waitcnt lgkmcnt(0)" ::: "memory");  // same-wave WAR/RAW
    const int batch = brow >> 11;
    bf16_t* vt = vT + (size_t)batch * HID * SEQ;
    const int c0 = bcol + wn * 64;
    const int s0 = (brow & 2047) + wm * 64;
    const int lr = lane >> 3, lc = (lane & 7) * 8;
#pragma unroll
    for (int p = 0; p < 8; ++p) {
      const int rt = p * 8 + lr;  // tileT row = vT col offset
      const bf16x8 vv = *(const bf16x8*)(tp + rt * 72 + lc);
      *(bf16x8*)(vt + (size_t)(c0 + rt) * SEQ + s0 + lc) = vv;
    }
  }
#undef SA
#undef SB
}

// ---------------------------------------------------------------------------
// QK / PV GEMM: 256^2 4-phase 16x16 structure.
// EPI 1 (QK): P = mask ? exp(s/32) : 0 (bf16, unnormalized); fused rowsum:
//   16-lane shfl reduce per row + one atomicAdd per row per wave into rsum.
// EPI 2 (PV split-K2): out = acc / rsum[row] (bf16 partial).
// ---------------------------------------------------------------------------
template <int EPI>
__global__ __launch_bounds__(512, 2) void gemm8(
    const bf16_t* __restrict__ Ab, const bf16_t* __restrict__ B0,
    const int* __restrict__ maskp, float* __restrict__ rsum,
    bf16_t* __restrict__ o0, bf16_t* __restrict__ o1) {
  constexpr int TM = 8;
  constexpr int TN = (EPI == 1) ? 8 : 4;
  constexpr int LDA = (EPI == 2) ? SEQ : HID;
  constexpr int LDB = (EPI == 2) ? SEQ : HID;
  constexpr int LDC = (EPI == 1) ? SEQ : HID;
  constexpr int NT = 16;

  __shared__ bf16_t lA[2 * 16384];
  __shared__ bf16_t lB[2 * 16384];

  const int nwg = gridDim.x;
  int Lb = blockIdx.x;
  Lb = (Lb & 7) * (nwg >> 3) + (Lb >> 3);
  const int z = Lb / (TM * TN);
  const int rem = Lb - z * (TM * TN);
  const int tm = rem / TN;
  const int tn = rem - tm * TN;
  const int brow = tm * 256, bcol = tn * 256;

  const bf16_t* A;
  const bf16_t* B;
  bf16_t* outb;
  int zb = 0;
  if (EPI == 1) {
    A = Ab + (size_t)z * SEQ * HID;
    B = B0 + (size_t)z * SEQ * HID;
    outb = o0 + (size_t)z * SEQ * SEQ;
  } else {
    zb = z >> 1;
    const int kh = z & 1;
    A = Ab + (size_t)zb * SEQ * SEQ + kh * 1024;  // scores K-half
    B = B0 + (size_t)zb * HID * SEQ + kh * 1024;  // vT K-half
    outb = ((kh == 0) ? o0 : o1) + (size_t)zb * SEQ * HID;
  }

  const int t = threadIdx.x, wave = t >> 6, lane = t & 63;
  const int wm = wave >> 2, wn = wave & 3;
  const int fr = lane & 15, kb = lane >> 4;
  const int srow = t >> 3;
  const int cbk = (t & 7) ^ (srow & 7);
  const bf16_t* pAs = A + (size_t)(brow + srow) * LDA + cbk * 8;
  const bf16_t* pBs = B + (size_t)(bcol + srow) * LDB + cbk * 8;
  bf16_t* lAw = lA + wave * 512;
  bf16_t* lBw = lB + wave * 512;

#define SA(X_, h_)                                                  \
  gload_lds16(pAs + (size_t)((h_)*64) * LDA + (X_)*64,              \
              lAw + ((X_)&1) * 16384 + (h_)*4096)
#define SB(X_, h_)                                                  \
  gload_lds16(pBs + (size_t)((h_)*64) * LDB + (X_)*64,              \
              lBw + ((X_)&1) * 16384 + (h_)*4096)

  const char* lAc = (const char*)lA;
  const char* lBc = (const char*)lB;
  const int cX0 = ((kb ^ (fr & 7)) << 4);
  const int cX1 = cX0 ^ 64;
  const int bRowOff = (wn & 1) * 64;

  f32x4 acc[8][4] = {};

  SA(0, 0); SA(0, 1); SA(0, 2); SA(0, 3);
  SB(0, 0); SB(0, 1); SB(0, 2); SB(0, 3);
  SA(1, 0); SA(1, 2);
  SB(1, 0); SB(1, 1); SB(1, 2); SB(1, 3);
  asm volatile("s_waitcnt vmcnt(6)" ::: "memory");
  __builtin_amdgcn_s_barrier();

  for (int kt = 0; kt < NT; ++kt) {
    const char* aB = lAc + (kt & 1) * 32768 + wm * 16384;
    const char* bB = lBc + (kt & 1) * 32768 + (wn >> 1) * 16384;
    bf16x8 bf_[4][2];
#pragma unroll
    for (int p = 0; p < 4; ++p) {
      if (p == 0) {
#pragma unroll
        for (int n = 0; n < 4; ++n) {
          const int rb = (bRowOff + n * 16 + fr) * 128;
          bf_[n][0] = *(const bf16x8*)(bB + rb + cX0);
          bf_[n][1] = *(const bf16x8*)(bB + rb + cX1);
        }
      }
      const int ra0 = (p * 32 + fr) * 128;
      const int ra1 = (p * 32 + 16 + fr) * 128;
      bf16x8 a00 = *(const bf16x8*)(aB + ra0 + cX0);
      bf16x8 a01 = *(const bf16x8*)(aB + ra0 + cX1);
      bf16x8 a10 = *(const bf16x8*)(aB + ra1 + cX0);
      bf16x8 a11 = *(const bf16x8*)(aB + ra1 + cX1);
      if (p == 0 && kt + 1 < NT) { SA(kt + 1, 1); SA(kt + 1, 3); }
      if (p == 1 && kt + 2 < NT) { SB(kt + 2, 0); SB(kt + 2, 1); }
      if (p == 2 && kt + 2 < NT) { SA(kt + 2, 0); SA(kt + 2, 2); }
      if (p == 3 && kt + 2 < NT) { SB(kt + 2, 2); SB(kt + 2, 3); }
      __builtin_amdgcn_s_barrier();
      __builtin_amdgcn_s_setprio(1);
#pragma unroll
      for (int n = 0; n < 4; ++n) {
        acc[2 * p][n] = mfma16(a00, bf_[n][0], acc[2 * p][n]);
        acc[2 * p][n] = mfma16(a01, bf_[n][1], acc[2 * p][n]);
        acc[2 * p + 1][n] = mfma16(a10, bf_[n][0], acc[2 * p + 1][n]);
        acc[2 * p + 1][n] = mfma16(a11, bf_[n][1], acc[2 * p + 1][n]);
      }
      __builtin_amdgcn_s_setprio(0);
      if (p == 3) {
        if (kt < NT - 3)
          asm volatile("s_waitcnt vmcnt(6)" ::: "memory");
        else
          asm volatile("s_waitcnt vmcnt(0)" ::: "memory");
      }
      __builtin_amdgcn_s_barrier();
    }
  }

  // C/D layout (m89): col = lane&15, row = (lane>>4)*4 + j
  const int qr = lane >> 4;
  const int crow = brow + wm * 128 + qr * 4;
  const int ccol = bcol + wn * 64 + fr;
  if (EPI == 1) {
    const int* mrow = maskp + (size_t)z * SEQ;
    float* rs = rsum + (size_t)z * SEQ;
    int mv[4];
#pragma unroll
    for (int n = 0; n < 4; ++n) mv[n] = mrow[ccol + n * 16];
#pragma unroll
    for (int m = 0; m < 8; ++m) {
      const int row = crow + m * 16;
#pragma unroll
      for (int j = 0; j < 4; ++j) {
        float rp = 0.f;
#pragma unroll
        for (int n = 0; n < 4; ++n) {
          const int col = ccol + n * 16;
          const float p = mv[n] ? __expf(acc[m][n][j] * 0.03125f) : 0.f;
          outb[(size_t)(row + j) * LDC + col] = (bf16_t)p;
          rp += p;
        }
        rp += __shfl_xor(rp, 1, 64);
        rp += __shfl_xor(rp, 2, 64);
        rp += __shfl_xor(rp, 4, 64);
        rp += __shfl_xor(rp, 8, 64);
        if (fr == 0) atomicAdd(&rs[row + j], rp);
      }
    }
  } else {
    const float* rv = rsum + (size_t)zb * SEQ;
#pragma unroll
    for (int m = 0; m < 8; ++m) {
      const int row = crow + m * 16;
#pragma unroll
      for (int j = 0; j < 4; ++j) {
        const float ri = 1.f / rv[row + j];
#pragma unroll
        for (int n = 0; n < 4; ++n) {
          const int col = ccol + n * 16;
          outb[(size_t)(row + j) * LDC + col] = (bf16_t)(acc[m][n][j] * ri);
        }
      }
    }
  }
#undef SA
#undef SB
}

// ---------------------------------------------------------------------------
// merged casts: y=0..2 -> Wq/Wk/Wv, y=3 -> x
__global__ __launch_bounds__(256) void cast4(
    const float* __restrict__ s0, const float* __restrict__ s1,
    const float* __restrict__ s2, const float* __restrict__ s3,
    bf16_t* __restrict__ d0, bf16_t* __restrict__ d1,
    bf16_t* __restrict__ d2, bf16_t* __restrict__ d3, long nW4, long nX4) {
  const int y = blockIdx.y;
  const float* in = (y == 0) ? s0 : (y == 1) ? s1 : (y == 2) ? s2 : s3;
  bf16_t* out = (y == 0) ? d0 : (y == 1) ? d1 : (y == 2) ? d2 : d3;
  const long n4 = (y == 3) ? nX4 : nW4;
  const long stride = (long)gridDim.x * blockDim.x;
  for (long i = (long)blockIdx.x * blockDim.x + threadIdx.x; i < n4;
       i += stride) {
    f32x4 x = *(const f32x4*)(in + i * 4);
    bf16x4 o;
#pragma unroll
    for (int j = 0; j < 4; ++j) o[j] = (bf16_t)x[j];
    *(bf16x4*)(out + i * 4) = o;
  }
}

// y = resid + attn0 + attn1; LayerNorm(y).
// resid source: xinf (f32, layer 0) else xinb (bf16). Outputs: optional f32
// xout (final layer) and/or bf16 xbout (next layer input; may alias xinb).
__global__ __launch_bounds__(256) void resid_ln(
    const bf16_t* __restrict__ part0, const bf16_t* __restrict__ part1,
    const float* __restrict__ xinf, const bf16_t* __restrict__ xinb,
    const float* __restrict__ lnw, const float* __restrict__ lnb,
    float* __restrict__ xout, bf16_t* __restrict__ xbout) {
  const int row = blockIdx.x;
  const int t = threadIdx.x;
  const int wave = t >> 6;
  const int lane = t & 63;
  const size_t base = (size_t)row * HID + t * 4;
  const bf16x4 a0 = *(const bf16x4*)(part0 + base);
  const bf16x4 a1 = *(const bf16x4*)(part1 + base);
  f32x4 xv;
  if (xinf != nullptr) {
    xv = *(const f32x4*)(xinf + base);
  } else {
    const bf16x4 xbv = *(const bf16x4*)(xinb + base);
#pragma unroll
    for (int j = 0; j < 4; ++j) xv[j] = (float)xbv[j];
  }
  f32x4 y;
#pragma unroll
  for (int j = 0; j < 4; ++j) y[j] = (float)a0[j] + (float)a1[j] + xv[j];
  float s1 = y[0] + y[1] + y[2] + y[3];
  float s2 = y[0] * y[0] + y[1] * y[1] + y[2] * y[2] + y[3] * y[3];
#pragma unroll
  for (int off = 32; off > 0; off >>= 1) {
    s1 += __shfl_xor(s1, off, 64);
    s2 += __shfl_xor(s2, off, 64);
  }
  __shared__ float red[8];
  if (lane == 0) {
    red[wave] = s1;
    red[4 + wave] = s2;
  }
  __syncthreads();
  s1 = red[0] + red[1] + red[2] + red[3];
  s2 = red[4] + red[5] + red[6] + red[7];
  const float mu = s1 * (1.f / HID);
  const float var = s2 * (1.f / HID) - mu * mu;
  const float rs = rsqrtf(var + LN_EPS);
  const f32x4 wv = *(const f32x4*)(lnw + t * 4);
  const f32x4 bv = *(const f32x4*)(lnb + t * 4);
  f32x4 o;
#pragma unroll
  for (int j = 0; j < 4; ++j) o[j] = wv[j] * ((y[j] - mu) * rs) + bv[j];
  if (xout != nullptr) *(f32x4*)(xout + base) = o;
  if (xbout != nullptr) {
    bf16x4 ob;
#pragma unroll
    for (int j = 0; j < 4; ++j) ob[j] = (bf16_t)o[j];
    *(bf16x4*)(xbout + base) = ob;
  }
}

// ---------------------------------------------------------------------------
extern "C" void kernel_launch(void* const* d_in, const int* in_sizes, int n_in,
                              void* d_out, int out_size, void* d_ws,
                              size_t ws_size, hipStream_t stream) {
  const float* x_in = (const float*)d_in[0];
  const int* mask = (const int*)d_in[1];
  const float* Wq = (const float*)d_in[2];
  const float* bq = (const float*)d_in[3];
  const float* Wk = (const float*)d_in[4];
  const float* bk = (const float*)d_in[5];
  const float* Wv = (const float*)d_in[6];
  const float* bv = (const float*)d_in[7];
  const float* lnw = (const float*)d_in[8];
  const float* lnb = (const float*)d_in[9];
  float* out = (float*)d_out;

  char* ws = (char*)d_ws;
  size_t off = 0;
  auto alloc = [&](size_t bytes) {
    char* p = ws + off;
    off += (bytes + 255) & ~(size_t)255;
    return (void*)p;
  };
  const size_t LHH = (size_t)NL * HID * HID;
  bf16_t* wqb = (bf16_t*)alloc(LHH * 2);
  bf16_t* wkb = (bf16_t*)alloc(LHH * 2);
  bf16_t* wvb = (bf16_t*)alloc(LHH * 2);
  bf16_t* xb = (bf16_t*)alloc((size_t)MR * HID * 2);
  bf16_t* q = (bf16_t*)alloc((size_t)MR * HID * 2);
  bf16_t* k = (bf16_t*)alloc((size_t)MR * HID * 2);
  bf16_t* vT = (bf16_t*)alloc((size_t)MR * HID * 2);
  bf16_t* scores = (bf16_t*)alloc((size_t)BB * SEQ * SEQ * 2);
  bf16_t* attn0 = (bf16_t*)alloc((size_t)MR * HID * 2);
  bf16_t* attn1 = (bf16_t*)alloc((size_t)MR * HID * 2);
  float* rsum = (float*)alloc((size_t)MR * 4);
  if (off > ws_size) return;

  cast4<<<dim3(1024, 4), 256, 0, stream>>>(Wq, Wk, Wv, x_in, wqb, wkb, wvb, xb,
                                           (long)(LHH / 4),
                                           (long)((size_t)MR * HID / 4));

  for (int l = 0; l < NL; ++l) {
    const size_t wo = (size_t)l * HID * HID;
    // QKV: grid 32*8*3 = 768, z-outer decode; V written transposed (LDS xp)
    gemm_qkv<<<768, 512, 0, stream>>>(xb, wqb + wo, wkb + wo, wvb + wo,
                                      bq + (size_t)l * HID,
                                      bk + (size_t)l * HID,
                                      bv + (size_t)l * HID, q, k, vT);
    // rsum = 0, then P = mask*exp(qk^T/32) with fused atomic rowsum
    hipMemsetAsync(rsum, 0, (size_t)MR * 4, stream);
    gemm8<1><<<256, 512, 0, stream>>>(q, k, mask, rsum, scores, nullptr);
    // attn partials = (P @ v) / rsum (split-K 2)
    gemm8<2><<<256, 512, 0, stream>>>(scores, vT, nullptr, rsum, attn0, attn1);
    // residual + LayerNorm
    const float* xif = (l == 0) ? x_in : nullptr;
    float* xo = (l == NL - 1) ? out : nullptr;
    bf16_t* xbo = (l == NL - 1) ? nullptr : xb;
    resid_ln<<<MR, 256, 0, stream>>>(attn0, attn1, xif, xb,
                                     lnw + (size_t)l * HID,
                                     lnb + (size_t)l * HID, xo, xbo);
  }
}